// Round 4
// baseline (636.507 us; speedup 1.0000x reference)
//
#include <hip/hip_runtime.h>

#define B_   4
#define C_   256
#define C2_  128
#define HIN  128
#define HO   63
#define NSEQ 3969          // 63*63
#define NPAD 4032          // 63*64
#define QPAD 4096
#define D_   128
#define TOT  (B_*C_*NSEQ)  // 4064256
#define SPLITS 3

typedef _Float16 f16x8 __attribute__((ext_vector_type(8)));
typedef short    s16x8 __attribute__((ext_vector_type(8)));
typedef float    f32x4 __attribute__((ext_vector_type(4)));
typedef unsigned short u16;
typedef u16 u16x8 __attribute__((ext_vector_type(8)));

#define MFMA16(a,b,c) __builtin_amdgcn_mfma_f32_16x16x32_f16((a),(b),(c),0,0,0)
#define MFMABF(a,b,c) __builtin_amdgcn_mfma_f32_16x16x32_bf16((a),(b),(c),0,0,0)

__device__ __forceinline__ float b2f(u16 u) {
  unsigned v = ((unsigned)u) << 16;
  return __builtin_bit_cast(float, v);
}
__device__ __forceinline__ u16 f2b(float f) {
  unsigned u = __builtin_bit_cast(unsigned, f);
  return (u16)((u + 0x7FFFu + ((u >> 16) & 1u)) >> 16);
}

template<int CTRL>
__device__ __forceinline__ float dppf(float x) {
  return __builtin_bit_cast(float,
      __builtin_amdgcn_mov_dpp(__builtin_bit_cast(int, x), CTRL, 0xF, 0xF, true));
}
__device__ __forceinline__ float rmax16(float x) {
  x = fmaxf(x, dppf<0xB1>(x));
  x = fmaxf(x, dppf<0x4E>(x));
  x = fmaxf(x, dppf<0x124>(x));
  x = fmaxf(x, dppf<0x128>(x));
  return x;
}
__device__ __forceinline__ float rsum16(float x) {
  x += dppf<0xB1>(x);
  x += dppf<0x4E>(x);
  x += dppf<0x124>(x);
  x += dppf<0x128>(x);
  return x;
}

// ========== pool_k: self-detect dtype + maxpool 3x3/s2 + bf16 transpose ==========
// grid (63 h, 4 cgroups, B), 256 thr. Also: block(0,0,0) writes flag, zeros stats.
template<bool BF>
__device__ void pool_body(const void* x, void* xp, u16* xpT,
                          int h, int cg, int b, int tid, u16* Tls) {
  int cl = tid >> 2, w0 = (tid & 3) << 4;
  int c = cg * 64 + cl;
  long rowbase = ((long)(b * C_ + c) * HIN + 2 * h) * HIN + 2 * w0;
  float best[16];
#pragma unroll
  for (int j = 0; j < 16; j++) best[j] = -3e38f;
#pragma unroll
  for (int dh = 0; dh < 3; dh++) {
    long ro = rowbase + dh * HIN;
    float v[40];
    if (BF) {
#pragma unroll
      for (int ch = 0; ch < 5; ch++) {
        u16x8 a = *(const u16x8*)((const u16*)x + ro + ch * 8);
#pragma unroll
        for (int j = 0; j < 8; j++) v[ch * 8 + j] = b2f(a[j]);
      }
    } else {
#pragma unroll
      for (int ch = 0; ch < 10; ch++) {
        f32x4 a = *(const f32x4*)((const float*)x + ro + ch * 4);
#pragma unroll
        for (int j = 0; j < 4; j++) v[ch * 4 + j] = a[j];
      }
    }
#pragma unroll
    for (int j = 0; j < 16; j++)
      best[j] = fmaxf(best[j], fmaxf(fmaxf(v[2 * j], v[2 * j + 1]), v[2 * j + 2]));
  }
  long xo = (long)(b * C_ + c) * NPAD + h * HO + w0;
  if (BF) {
    u16 arr[16];
#pragma unroll
    for (int j = 0; j < 16; j++) arr[j] = f2b(best[j]);
    if (w0 < 48) {
      *(u16x8*)((u16*)xp + xo) = *(u16x8*)&arr[0];
      *(u16x8*)((u16*)xp + xo + 8) = *(u16x8*)&arr[8];
    } else {
      *(u16x8*)((u16*)xp + xo) = *(u16x8*)&arr[0];
#pragma unroll
      for (int j = 8; j < 15; j++) ((u16*)xp)[xo + j] = arr[j];   // w0+15 == 63 dropped
    }
#pragma unroll
    for (int j = 0; j < 16; j++) Tls[cl * 68 + w0 + j] = arr[j];
    __syncthreads();
    int w = tid >> 2, cc0 = (tid & 3) << 4;
    if (w < HO) {
      u16x8 o0, o1;
#pragma unroll
      for (int j = 0; j < 8; j++) o0[j] = Tls[(cc0 + j) * 68 + w];
#pragma unroll
      for (int j = 0; j < 8; j++) o1[j] = Tls[(cc0 + 8 + j) * 68 + w];
      u16* d = xpT + ((long)b * NPAD + h * HO + w) * C_ + cg * 64 + cc0;
      *(u16x8*)d = o0;
      *(u16x8*)(d + 8) = o1;
    }
  } else {
    float* o = (float*)xp;
    if (w0 < 48) {
#pragma unroll
      for (int q = 0; q < 4; q++)
        *(f32x4*)(o + xo + q * 4) = (f32x4){best[q*4], best[q*4+1], best[q*4+2], best[q*4+3]};
    } else {
#pragma unroll
      for (int j = 0; j < 15; j++) o[xo + j] = best[j];
    }
  }
}
__global__ __launch_bounds__(256) void pool_k(const void* x, void* xp, u16* xpT,
                                              int* flag, float* gsum, float* gsq) {
  __shared__ u16 Tls[64 * 68];
  __shared__ int cnt;
  int tid = threadIdx.x;
  if (tid == 0) cnt = 0;
  __syncthreads();
  const u16* u = (const u16*)x;
  int cc = 0;
  for (int i = tid; i < 4096; i += 256) {
    int e = (u[i] >> 7) & 0xFF;
    if (e > 141) cc++;
  }
  atomicAdd(&cnt, cc);
  __syncthreads();
  bool bf = (cnt <= 64);
  if (blockIdx.x == 0 && blockIdx.y == 0 && blockIdx.z == 0) {
    gsum[tid] = 0.f;
    gsq[tid] = 0.f;
    if (tid == 0) flag[0] = bf ? 1 : 0;
  }
  int h = blockIdx.x, cg = blockIdx.y, b = blockIdx.z;
  if (bf) pool_body<true>(x, xp, xpT, h, cg, b, tid, Tls);
  else    pool_body<false>(x, xp, xpT, h, cg, b, tid, Tls);
}

// ========== qkv_k: bf16 MFMA path + fp32 vector fallback in one kernel ==========
// Q: [b][QPAD][128] f16 hi/lo. K: [b][NPAD][128] f16. V: [b][128][NPAD] f16.
__global__ __launch_bounds__(256) void qkv_k(
    const void* xp, const u16* __restrict__ xpT,
    const void* tw, const void* pw, const void* gw,
    _Float16* Qh, _Float16* Ql, _Float16* Kv, _Float16* Vt, const int* flag) {
  __shared__ u16 Asm[64 * 256];
  __shared__ u16 Bsm[64 * 256];
  __shared__ float Tsm[4][16][64];
  int pt = blockIdx.x, y = blockIdx.y, b = blockIdx.z;
  int tid = threadIdx.x, wave = tid >> 6, lane = tid & 63;
  int quad = lane >> 4, l16 = lane & 15;
  int mat = y >> 1, half = y & 1;
  if (flag[0]) {
    const u16* W  = (const u16*)((mat == 0) ? tw : (mat == 1) ? pw : gw);
    const u16* Wr = W + (long)(half * 64) * C_;
    const u16* Xb = xpT + ((long)b * NPAD + pt * 64) * C_;
#pragma unroll
    for (int i = 0; i < 8; i++) {
      int g = tid + i * 256;
      int r = g >> 5, ccc = g & 31;
      int sw = (ccc ^ (r & 15)) << 3;
      *(u16x8*)&Asm[r * 256 + sw] = *(const u16x8*)(Wr + (long)r * C_ + ccc * 8);
      *(u16x8*)&Bsm[r * 256 + sw] = *(const u16x8*)(Xb + (long)r * C_ + ccc * 8);
    }
    __syncthreads();
    f32x4 acc[4];
#pragma unroll
    for (int s = 0; s < 4; s++) acc[s] = (f32x4){0.f, 0.f, 0.f, 0.f};
#pragma unroll
    for (int kc = 0; kc < 8; kc++) {
      s16x8 a = *(const s16x8*)&Asm[(wave * 16 + l16) * 256 + (((kc * 4 + quad) ^ l16) << 3)];
#pragma unroll
      for (int s = 0; s < 4; s++) {
        s16x8 bfv = *(const s16x8*)&Bsm[(s * 16 + l16) * 256 + (((kc * 4 + quad) ^ l16) << 3)];
        acc[s] = MFMABF(a, bfv, acc[s]);
      }
    }
    int chanb = half * 64 + wave * 16;
    if (mat == 2) {
      _Float16* dv = Vt + (long)b * C2_ * NPAD;
#pragma unroll
      for (int s = 0; s < 4; s++)
#pragma unroll
        for (int r = 0; r < 4; r++) {
          int p = pt * 64 + s * 16 + l16;
          if (p < NSEQ) dv[(long)(chanb + quad * 4 + r) * NPAD + p] = (_Float16)acc[s][r];
        }
    } else {
#pragma unroll
      for (int s = 0; s < 4; s++)
#pragma unroll
        for (int r = 0; r < 4; r++)
          Tsm[wave][quad * 4 + r][s * 16 + l16] = acc[s][r];
      int p = pt * 64 + lane;
      if (p < NSEQ) {
        f16x8 hv[2], lv[2];
#pragma unroll
        for (int cl = 0; cl < 16; cl++) {
          float v = Tsm[wave][cl][lane];
          _Float16 hx = (_Float16)v;
          hv[cl >> 3][cl & 7] = hx;
          lv[cl >> 3][cl & 7] = (_Float16)(v - (float)hx);
        }
        if (mat == 0) {
          _Float16* dh = Qh + ((long)b * QPAD + p) * 128 + chanb;
          _Float16* dl = Ql + ((long)b * QPAD + p) * 128 + chanb;
          *(f16x8*)dh = hv[0]; *(f16x8*)(dh + 8) = hv[1];
          *(f16x8*)dl = lv[0]; *(f16x8*)(dl + 8) = lv[1];
        } else {
          _Float16* dk = Kv + ((long)b * NPAD + p) * 128 + chanb;
          *(f16x8*)dk = hv[0]; *(f16x8*)(dk + 8) = hv[1];
        }
      }
    }
  } else {
    // fp32 vector fallback (perf non-critical)
    const float* W = (const float*)((mat == 0) ? tw : (mat == 1) ? pw : gw);
    int p = pt * 64 + lane;
    int oc0 = half * 64 + wave * 16;
    const float* xb = (const float*)xp + (long)b * C_ * NPAD;
    float acc[16];
#pragma unroll
    for (int r = 0; r < 16; r++) acc[r] = 0.f;
    for (int c = 0; c < C_; c++) {
      float xv = xb[(long)c * NPAD + p];
#pragma unroll
      for (int r = 0; r < 16; r++) acc[r] += W[(oc0 + r) * C_ + c] * xv;
    }
    if (p < NSEQ) {
      if (mat < 2) {
        f16x8 hv[2], lv[2];
#pragma unroll
        for (int r = 0; r < 16; r++) {
          _Float16 hx = (_Float16)acc[r];
          hv[r >> 3][r & 7] = hx;
          lv[r >> 3][r & 7] = (_Float16)(acc[r] - (float)hx);
        }
        if (mat == 0) {
          _Float16* dh = Qh + ((long)b * QPAD + p) * 128 + oc0;
          _Float16* dl = Ql + ((long)b * QPAD + p) * 128 + oc0;
          *(f16x8*)dh = hv[0]; *(f16x8*)(dh + 8) = hv[1];
          *(f16x8*)dl = lv[0]; *(f16x8*)(dl + 8) = lv[1];
        } else {
          _Float16* dk = Kv + ((long)b * NPAD + p) * 128 + oc0;
          *(f16x8*)dk = hv[0]; *(f16x8*)(dk + 8) = hv[1];
        }
      } else {
        _Float16* dv = Vt + (long)b * C2_ * NPAD;
#pragma unroll
        for (int r = 0; r < 16; r++)
          dv[(long)(oc0 + r) * NPAD + p] = (_Float16)acc[r];
      }
    }
  }
}

// ========== flash v4: BM=64, 32 KB LDS (Ps aliases Ks), 3 barriers, 3 waves/SIMD ==========
__global__ __launch_bounds__(256, 3) void flash_k(
    const _Float16* __restrict__ Qh, const _Float16* __restrict__ Ql,
    const _Float16* __restrict__ Kv, const _Float16* __restrict__ Vt,
    float* __restrict__ Opart, float* __restrict__ Mp, float* __restrict__ Lp) {
  __shared__ _Float16 Ks[64 * 128];   // 16 KB; after barrier C reused as Ps (per-wave 2 KB)
  __shared__ _Float16 Vs[128 * 64];   // 16 KB
  int qt = blockIdx.x, split = blockIdx.y, b = blockIdx.z;
  int tid = threadIdx.x, wave = tid >> 6, lane = tid & 63;
  int quad = lane >> 4, l16 = lane & 15;
  const _Float16* Qhb = Qh + (long)b * QPAD * D_;
  const _Float16* Qlb = Ql + (long)b * QPAD * D_;
  const _Float16* Kb  = Kv + (long)b * NPAD * D_;
  const _Float16* Vb  = Vt + (long)b * C2_ * NPAD;

  long qrow = qt * 64 + wave * 16 + l16;
  f16x8 aqh[4], aql[4];
#pragma unroll
  for (int kk = 0; kk < 4; kk++) {
    aqh[kk] = *(const f16x8*)(Qhb + qrow * D_ + kk * 32 + quad * 8);
    aql[kk] = *(const f16x8*)(Qlb + qrow * D_ + kk * 32 + quad * 8);
  }
  f32x4 o_acc[8];
#pragma unroll
  for (int s = 0; s < 8; s++) o_acc[s] = (f32x4){0.f, 0.f, 0.f, 0.f};
  float m_r[4] = {-3e38f, -3e38f, -3e38f, -3e38f};
  float l_r[4] = {0.f, 0.f, 0.f, 0.f};
  const float LOG2E = 1.4426950408889634f;
  int po = wave * 1024;               // Ps region inside Ks

  int t0 = split * 21, t1 = t0 + 21;
  for (int t = t0; t < t1; t++) {
    __syncthreads();                  // (A) prior PV reads of Ps(=Ks)/Vs done
#pragma unroll
    for (int i = 0; i < 4; i++) {     // stage K,V; swizzle on the LDS-address side
      int g = tid + i * 256;          // 0..1023
      int r = g >> 4, q = g & 15;
      *(f16x8*)&Ks[r * 128 + ((q ^ (r & 15)) << 3)] =
          *(const f16x8*)(Kb + (long)(t * 64 + r) * D_ + q * 8);
      int c = g >> 3, q8 = g & 7;
      *(f16x8*)&Vs[c * 64 + ((q8 ^ (c & 7)) << 3)] =
          *(const f16x8*)(Vb + (long)c * NPAD + t * 64 + q8 * 8);
    }
    __syncthreads();                  // (B) tiles visible

    f32x4 s_acc[4];
#pragma unroll
    for (int s = 0; s < 4; s++) s_acc[s] = (f32x4){0.f, 0.f, 0.f, 0.f};
#pragma unroll
    for (int kk = 0; kk < 4; kk++) {
      f16x8 bh[4];
#pragma unroll
      for (int s = 0; s < 4; s++)
        bh[s] = *(const f16x8*)&Ks[(s * 16 + l16) * 128 + (((kk * 4 + quad) ^ l16) << 3)];
#pragma unroll
      for (int s = 0; s < 4; s++) s_acc[s] = MFMA16(aqh[kk], bh[s], s_acc[s]);
#pragma unroll
      for (int s = 0; s < 4; s++) s_acc[s] = MFMA16(aql[kk], bh[s], s_acc[s]);
    }
    __syncthreads();                  // (C) all QK reads of Ks done -> Ks reusable as Ps

#pragma unroll
    for (int s = 0; s < 4; s++) {
      if (t * 64 + s * 16 + l16 >= NSEQ) {
#pragma unroll
        for (int r = 0; r < 4; r++) s_acc[s][r] = -3e38f;
      }
    }
    float mx[4];
#pragma unroll
    for (int r = 0; r < 4; r++) {
      mx[r] = fmaxf(fmaxf(s_acc[0][r], s_acc[1][r]), fmaxf(s_acc[2][r], s_acc[3][r]));
      mx[r] = rmax16(mx[r]);
    }
    float alpha[4];
#pragma unroll
    for (int r = 0; r < 4; r++) {
      float mn = fmaxf(m_r[r], mx[r]);
      alpha[r] = exp2f((m_r[r] - mn) * LOG2E);
      m_r[r] = mn;
    }
    float pvv[4][4], rs[4] = {0.f, 0.f, 0.f, 0.f};
#pragma unroll
    for (int s = 0; s < 4; s++)
#pragma unroll
      for (int r = 0; r < 4; r++) {
        float p = exp2f((s_acc[s][r] - m_r[r]) * LOG2E);
        pvv[s][r] = p;
        rs[r] += p;
      }
#pragma unroll
    for (int r = 0; r < 4; r++) {
      rs[r] = rsum16(rs[r]);
      l_r[r] = l_r[r] * alpha[r] + rs[r];
    }
#pragma unroll
    for (int s8 = 0; s8 < 8; s8++)
#pragma unroll
      for (int r = 0; r < 4; r++) o_acc[s8][r] *= alpha[r];
    // P: C-layout -> per-wave swizzled LDS (wave-local, no barrier)
#pragma unroll
    for (int s = 0; s < 4; s++)
#pragma unroll
      for (int r = 0; r < 4; r++) {
        int m = quad * 4 + r;
        Ks[po + m * 64 + (((s * 2 + (l16 >> 3)) ^ (m & 7)) << 3) + (l16 & 7)] =
            (_Float16)pvv[s][r];
      }
    f16x8 ap[2];
#pragma unroll
    for (int kk2 = 0; kk2 < 2; kk2++)
      ap[kk2] = *(const f16x8*)&Ks[po + l16 * 64 + (((kk2 * 4 + quad) ^ (l16 & 7)) << 3)];
#pragma unroll
    for (int kk2 = 0; kk2 < 2; kk2++)
#pragma unroll
      for (int s8 = 0; s8 < 8; s8++) {
        int c2 = s8 * 16 + l16;
        f16x8 bv = *(const f16x8*)&Vs[c2 * 64 + (((kk2 * 4 + quad) ^ (c2 & 7)) << 3)];
        o_acc[s8] = MFMA16(ap[kk2], bv, o_acc[s8]);
      }
  }
  float* Ob = Opart + (long)(b * SPLITS + split) * NSEQ * D_;
  float* Mb = Mp + (long)(b * SPLITS + split) * NSEQ;
  float* Lb = Lp + (long)(b * SPLITS + split) * NSEQ;
#pragma unroll
  for (int r = 0; r < 4; r++) {
    int n = qt * 64 + wave * 16 + quad * 4 + r;
    if (n < NSEQ) {
#pragma unroll
      for (int s8 = 0; s8 < 8; s8++)
        Ob[(long)n * D_ + s8 * 16 + l16] = o_acc[s8][r];
      if (l16 == 0) { Mb[n] = m_r[r]; Lb[n] = l_r[r]; }
    }
  }
}

// ========== merge split partials ==========
__global__ __launch_bounds__(256) void merge_k(const float* __restrict__ Opart,
                                               const float* __restrict__ Mp,
                                               const float* __restrict__ Lp,
                                               float* __restrict__ Y) {
  int row = blockIdx.x * 4 + (threadIdx.x >> 6);
  int lane = threadIdx.x & 63;
  int b = row / NSEQ, n = row - b * NSEQ;
  const float LOG2E = 1.4426950408889634f;
  float ms[SPLITS], m = -3e38f;
#pragma unroll
  for (int s = 0; s < SPLITS; s++) {
    ms[s] = Mp[(long)(b * SPLITS + s) * NSEQ + n];
    m = fmaxf(m, ms[s]);
  }
  float den = 0.f, a0 = 0.f, a1 = 0.f;
  int d = lane * 2;
#pragma unroll
  for (int s = 0; s < SPLITS; s++) {
    float w = exp2f((ms[s] - m) * LOG2E);
    den += Lp[(long)(b * SPLITS + s) * NSEQ + n] * w;
    const float* O = Opart + ((long)(b * SPLITS + s) * NSEQ + n) * D_ + d;
    a0 += w * O[0];
    a1 += w * O[1];
  }
  float inv = 1.f / den;
  float* Yo = Y + ((long)b * NSEQ + n) * D_ + d;
  Yo[0] = a0 * inv;
  Yo[1] = a1 * inv;
}

// ========== y_w GEMM on raw-viewed y + BN partial stats ==========
template<bool BF>
__device__ void out_body(const float* __restrict__ Y, const void* yw, float* outp,
                         float* gsum, float* gsumsq) {
  int b = blockIdx.z, ot = blockIdx.y, pb = blockIdx.x, tid = threadIdx.x;
  __shared__ float Wt[C2_][16];
  __shared__ float red[2][16][4];
#pragma unroll
  for (int i = 0; i < 8; i++) {
    int g = tid + i * 256;
    int r = g >> 7, c = g & 127;
    Wt[c][r] = BF ? b2f(((const u16*)yw)[(ot * 16 + r) * C2_ + c])
                  : ((const float*)yw)[(ot * 16 + r) * C2_ + c];
  }
  __syncthreads();
  int p0 = pb * 512 + tid;
  const float* Yb = Y + (long)b * NSEQ * D_;
  bool val[2];
#pragma unroll
  for (int j = 0; j < 2; j++) val[j] = (p0 + j * 256) < NSEQ;
  float acc[16][2];
#pragma unroll
  for (int r = 0; r < 16; r++)
#pragma unroll
    for (int j = 0; j < 2; j++) acc[r][j] = 0.f;
  for (int c = 0; c < C2_; c++) {
    float xv[2];
#pragma unroll
    for (int j = 0; j < 2; j++) xv[j] = val[j] ? Yb[(long)c * NSEQ + p0 + j * 256] : 0.f;
#pragma unroll
    for (int r4 = 0; r4 < 4; r4++) {
      f32x4 w4 = *(const f32x4*)&Wt[c][r4 * 4];
#pragma unroll
      for (int rr = 0; rr < 4; rr++)
#pragma unroll
        for (int j = 0; j < 2; j++) acc[r4 * 4 + rr][j] += w4[rr] * xv[j];
    }
  }
  long ob = ((long)b * C_ + ot * 16) * NSEQ;
#pragma unroll
  for (int r = 0; r < 16; r++)
#pragma unroll
    for (int j = 0; j < 2; j++)
      if (val[j]) outp[ob + (long)r * NSEQ + p0 + j * 256] = acc[r][j];
  int wave = tid >> 6, lane = tid & 63;
#pragma unroll
  for (int r = 0; r < 16; r++) {
    float s = 0.f, q = 0.f;
#pragma unroll
    for (int j = 0; j < 2; j++) { s += acc[r][j]; q += acc[r][j] * acc[r][j]; }
#pragma unroll
    for (int off = 1; off < 64; off <<= 1) {
      s += __shfl_xor(s, off, 64);
      q += __shfl_xor(q, off, 64);
    }
    if (lane == 0) { red[0][r][wave] = s; red[1][r][wave] = q; }
  }
  __syncthreads();
  if (tid < 32) {
    int which = tid >> 4, r = tid & 15;
    float v = red[which][r][0] + red[which][r][1] + red[which][r][2] + red[which][r][3];
    atomicAdd((which ? gsumsq : gsum) + ot * 16 + r, v);
  }
}
__global__ __launch_bounds__(256) void out_k(const float* Y, const void* yw, float* outp,
                                             float* gsum, float* gsumsq, const int* flag) {
  if (flag[0]) out_body<true>(Y, yw, outp, gsum, gsumsq);
  else         out_body<false>(Y, yw, outp, gsum, gsumsq);
}

// ========== BN (training) + residual + relu ==========
template<bool BF>
__device__ void bn_body(const float* outp, const float* gsum, const float* gsumsq,
                        const void* bnw, const void* bnb, const void* xp, void* out) {
  int idx = blockIdx.x * 256 + threadIdx.x;
  if (idx >= TOT) return;
  int p = idx % NSEQ;
  int bc = idx / NSEQ;
  int c = bc & (C_ - 1);
  const float invn = 1.0f / (float)(B_ * NSEQ);
  float mean = gsum[c] * invn;
  float var = gsumsq[c] * invn - mean * mean;
  var = fmaxf(var, 0.f);
  float is = rsqrtf(var + 1e-5f);
  float w = BF ? b2f(((const u16*)bnw)[c]) : ((const float*)bnw)[c];
  float bb = BF ? b2f(((const u16*)bnb)[c]) : ((const float*)bnb)[c];
  float res = BF ? b2f(((const u16*)xp)[(long)bc * NPAD + p])
                 : ((const float*)xp)[(long)bc * NPAD + p];
  float v = (outp[idx] - mean) * is * w + bb + res;
  v = fmaxf(v, 0.f);
  if (BF) ((u16*)out)[idx] = f2b(v);
  else    ((float*)out)[idx] = v;
}
__global__ __launch_bounds__(256) void bn_k(const float* outp, const float* gsum, const float* gsumsq,
                                            const void* bnw, const void* bnb, const void* xp,
                                            void* out, const int* flag) {
  if (flag[0]) bn_body<true>(outp, gsum, gsumsq, bnw, bnb, xp, out);
  else         bn_body<false>(outp, gsum, gsumsq, bnw, bnb, xp, out);
}

// ========== launcher (6 graph nodes) ==========
extern "C" void kernel_launch(void* const* d_in, const int* in_sizes, int n_in,
                              void* d_out, int out_size, void* d_ws, size_t ws_size,
                              hipStream_t stream) {
  size_t off = 0;
  auto alloc = [&](size_t bytes) -> char* {
    char* p = (char*)d_ws + off;
    off += (bytes + 255) & ~(size_t)255;
    return p;
  };
  void*     xp   = alloc(sizeof(float) * (size_t)B_ * C_ * NPAD);          // 16.5 MB
  u16*      xpT  = (u16*)alloc(2 * (size_t)B_ * NPAD * C_);                // 8.3 MB (also Mp/Lp later)
  _Float16* Qh   = (_Float16*)alloc(2 * (size_t)B_ * QPAD * D_);           // 4.2 MB (Yb later)
  _Float16* Ql   = (_Float16*)alloc(2 * (size_t)B_ * QPAD * D_);           // 4.2 MB
  _Float16* Kv   = (_Float16*)alloc(2 * (size_t)B_ * NPAD * D_);           // 4.1 MB
  _Float16* Vt   = (_Float16*)alloc(2 * (size_t)B_ * C2_ * NPAD);          // 4.1 MB
  float*    big  = (float*)alloc(sizeof(float) * (size_t)B_ * SPLITS * NSEQ * D_); // 24.4 MB (Opart; then outp)
  float*    gsum = (float*)alloc(1024);
  float*    gsq  = (float*)alloc(1024);
  int*      flag = (int*)alloc(256);

  float* Mp = (float*)xpT;                               // xpT dead after qkv_k
  float* Lp = Mp + (size_t)B_ * SPLITS * NSEQ;
  float* Yb = (float*)Qh;                                // Qh+Ql dead after flash_k

  pool_k<<<dim3(63, 4, B_), 256, 0, stream>>>(d_in[0], xp, xpT, flag, gsum, gsq);
  qkv_k<<<dim3(63, 6, B_), 256, 0, stream>>>(xp, xpT, d_in[1], d_in[2], d_in[3],
                                             Qh, Ql, Kv, Vt, flag);
  flash_k<<<dim3(63, SPLITS, B_), 256, 0, stream>>>(Qh, Ql, Kv, Vt, big, Mp, Lp);
  merge_k<<<3969, 256, 0, stream>>>(big, Mp, Lp, Yb);
  out_k<<<dim3(8, 16, B_), 256, 0, stream>>>(Yb, d_in[4], big, gsum, gsq, flag);
  bn_k<<<(TOT + 255) / 256, 256, 0, stream>>>(big, gsum, gsq, d_in[5], d_in[6], xp, d_out, flag);
}

// Round 5
// 309.036 us; speedup vs baseline: 2.0596x; 2.0596x over previous
//
#include <hip/hip_runtime.h>

#define B_   4
#define C_   256
#define C2_  128
#define HIN  128
#define HO   63
#define NSEQ 3969          // 63*63
#define NPAD 4032          // 63*64
#define QPAD 4096
#define D_   128
#define TOT  (B_*C_*NSEQ)  // 4064256
#define SPLITS 3

typedef _Float16 f16x8 __attribute__((ext_vector_type(8)));
typedef short    s16x8 __attribute__((ext_vector_type(8)));
typedef float    f32x4 __attribute__((ext_vector_type(4)));
typedef unsigned short u16;
typedef u16 u16x8 __attribute__((ext_vector_type(8)));

#define MFMA16(a,b,c) __builtin_amdgcn_mfma_f32_16x16x32_f16((a),(b),(c),0,0,0)
#define MFMABF(a,b,c) __builtin_amdgcn_mfma_f32_16x16x32_bf16((a),(b),(c),0,0,0)

__device__ __forceinline__ float b2f(u16 u) {
  unsigned v = ((unsigned)u) << 16;
  return __builtin_bit_cast(float, v);
}
__device__ __forceinline__ u16 f2b(float f) {   // RTN-even
  unsigned u = __builtin_bit_cast(unsigned, f);
  return (u16)((u + 0x7FFFu + ((u >> 16) & 1u)) >> 16);
}

template<int CTRL>
__device__ __forceinline__ float dppf(float x) {
  return __builtin_bit_cast(float,
      __builtin_amdgcn_mov_dpp(__builtin_bit_cast(int, x), CTRL, 0xF, 0xF, true));
}
__device__ __forceinline__ float rmax16(float x) {
  x = fmaxf(x, dppf<0xB1>(x));
  x = fmaxf(x, dppf<0x4E>(x));
  x = fmaxf(x, dppf<0x124>(x));
  x = fmaxf(x, dppf<0x128>(x));
  return x;
}
__device__ __forceinline__ float rsum16(float x) {
  x += dppf<0xB1>(x);
  x += dppf<0x4E>(x);
  x += dppf<0x124>(x);
  x += dppf<0x128>(x);
  return x;
}

// ========== pool_k: maxpool 3x3/s2 + transpose + bf16 hi/lo split ==========
// grid (63 h, 5, B). cg<4: pool 64 channels -> xp fp32 [bc][NPAD] and
// xpT2 [b][p][512] (k-interleaved hi/lo bf16). cg==4: split theta/phi/g
// weights into W2 [mat][oc][512]; block (0,4,0) also zeros BN stats.
__global__ __launch_bounds__(256) void pool_k(
    const float* __restrict__ x, float* __restrict__ xp, u16* __restrict__ xpT2,
    u16* __restrict__ W2, const float* __restrict__ tw, const float* __restrict__ pw,
    const float* __restrict__ gw, float* gsum, float* gsq) {
  __shared__ unsigned Tls[64 * 69];
  int h = blockIdx.x, cg = blockIdx.y, b = blockIdx.z;
  int tid = threadIdx.x;
  if (cg == 4) {                       // weight split (252 blocks, need 192)
    if (h == 0 && b == 0) { gsum[tid] = 0.f; gsq[tid] = 0.f; }
    int base = ((b * 63 + h) * 256 + tid) * 2;
#pragma unroll
    for (int e2 = 0; e2 < 2; e2++) {
      int e = base + e2;
      if (e < 3 * 128 * 256) {
        int mat = e >> 15, idx = e & 32767;
        int oc = idx >> 8, k = idx & 255;
        const float* W = (mat == 0) ? tw : (mat == 1) ? pw : gw;
        float v = W[oc * 256 + k];
        u16 hi = f2b(v);
        u16 lo = f2b(v - b2f(hi));
        W2[((long)(mat * 128 + oc)) * 512 + 2 * k]     = hi;
        W2[((long)(mat * 128 + oc)) * 512 + 2 * k + 1] = lo;
      }
    }
    return;
  }
  int cl = tid >> 2, w0 = (tid & 3) << 4;   // 64 channels x 4 w-groups of 16
  int c = cg * 64 + cl;
  long rowbase = ((long)(b * C_ + c) * HIN + 2 * h) * HIN + 2 * w0;
  float best[16];
#pragma unroll
  for (int j = 0; j < 16; j++) best[j] = -3e38f;
#pragma unroll
  for (int dh = 0; dh < 3; dh++) {
    long ro = rowbase + dh * HIN;
    float v[40];
#pragma unroll
    for (int ch = 0; ch < 10; ch++) {
      f32x4 a = *(const f32x4*)(x + ro + ch * 4);
#pragma unroll
      for (int j = 0; j < 4; j++) v[ch * 4 + j] = a[j];
    }
#pragma unroll
    for (int j = 0; j < 16; j++)
      best[j] = fmaxf(best[j], fmaxf(fmaxf(v[2 * j], v[2 * j + 1]), v[2 * j + 2]));
  }
  long xo = (long)(b * C_ + c) * NPAD + h * HO + w0;
#pragma unroll
  for (int j = 0; j < 16; j++)
    if (w0 + j < HO) xp[xo + j] = best[j];
#pragma unroll
  for (int j = 0; j < 16; j++) {
    u16 hi = f2b(best[j]);
    u16 lo = f2b(best[j] - b2f(hi));
    Tls[cl * 69 + w0 + j] = (unsigned)hi | ((unsigned)lo << 16);
  }
  __syncthreads();
  int w = tid >> 2, cc0 = (tid & 3) << 4;   // 64 w x 4 c-groups of 16
  if (w < HO) {
    int p = h * HO + w;
    u16 outv[32];
#pragma unroll
    for (int j = 0; j < 16; j++) {
      unsigned word = Tls[(cc0 + j) * 69 + w];
      outv[2 * j]     = (u16)(word & 0xFFFF);
      outv[2 * j + 1] = (u16)(word >> 16);
    }
    u16* d = xpT2 + ((long)b * NPAD + p) * 512 + 2 * (cg * 64 + cc0);
#pragma unroll
    for (int q = 0; q < 4; q++)
      *(u16x8*)(d + q * 8) = *(u16x8*)&outv[q * 8];
  }
}

// ========== qkv_k: K=512 bf16-split MFMA GEMM ==========
// grid (63 p-tiles, 6 = {theta,phi,g}x{half}, B).
// Q: [b][QPAD][128] f16 hi/lo. K: [b][NPAD][128] f16. V: [b][128][NPAD] f16.
__global__ __launch_bounds__(256) void qkv_k(
    const u16* __restrict__ xpT2, const u16* __restrict__ W2,
    _Float16* Qh, _Float16* Ql, _Float16* Kv, _Float16* Vt) {
  __shared__ u16 Asm[64 * 256];       // 32 KB, XOR-swizzled 16B chunks
  __shared__ u16 Bsm[64 * 256];       // 32 KB
  __shared__ float Tsm[4][16][64];    // 16 KB
  int pt = blockIdx.x, y = blockIdx.y, b = blockIdx.z;
  int tid = threadIdx.x, wave = tid >> 6, lane = tid & 63;
  int quad = lane >> 4, l16 = lane & 15;
  int mat = y >> 1, half = y & 1;
  const u16* Wr = W2 + ((long)(mat * 128 + half * 64)) * 512;
  const u16* Xb = xpT2 + ((long)b * NPAD + pt * 64) * 512;
  f32x4 acc[4];
#pragma unroll
  for (int s = 0; s < 4; s++) acc[s] = (f32x4){0.f, 0.f, 0.f, 0.f};
#pragma unroll
  for (int ck = 0; ck < 2; ck++) {    // two 256-wide K chunks of 512
    if (ck) __syncthreads();
#pragma unroll
    for (int i = 0; i < 8; i++) {
      int g = tid + i * 256;          // 0..2047
      int r = g >> 5, ccc = g & 31;
      int sw = (ccc ^ (r & 15)) << 3;
      *(u16x8*)&Asm[r * 256 + sw] = *(const u16x8*)(Wr + (long)r * 512 + ck * 256 + ccc * 8);
      *(u16x8*)&Bsm[r * 256 + sw] = *(const u16x8*)(Xb + (long)r * 512 + ck * 256 + ccc * 8);
    }
    __syncthreads();
#pragma unroll
    for (int kc = 0; kc < 8; kc++) {
      s16x8 a = *(const s16x8*)&Asm[(wave * 16 + l16) * 256 + (((kc * 4 + quad) ^ l16) << 3)];
#pragma unroll
      for (int s = 0; s < 4; s++) {
        s16x8 bv = *(const s16x8*)&Bsm[(s * 16 + l16) * 256 + (((kc * 4 + quad) ^ l16) << 3)];
        acc[s] = MFMABF(a, bv, acc[s]);
      }
    }
  }
  int chanb = half * 64 + wave * 16;
  if (mat == 2) {
    _Float16* dv = Vt + (long)b * C2_ * NPAD;
#pragma unroll
    for (int s = 0; s < 4; s++)
#pragma unroll
      for (int r = 0; r < 4; r++) {
        int p = pt * 64 + s * 16 + l16;
        if (p < NSEQ) dv[(long)(chanb + quad * 4 + r) * NPAD + p] = (_Float16)acc[s][r];
      }
  } else {
#pragma unroll
    for (int s = 0; s < 4; s++)
#pragma unroll
      for (int r = 0; r < 4; r++)
        Tsm[wave][quad * 4 + r][s * 16 + l16] = acc[s][r];
    int p = pt * 64 + lane;           // wave-local LDS roundtrip, no barrier
    if (p < NSEQ) {
      f16x8 hv[2], lv[2];
#pragma unroll
      for (int cl2 = 0; cl2 < 16; cl2++) {
        float v = Tsm[wave][cl2][lane];
        _Float16 hx = (_Float16)v;
        hv[cl2 >> 3][cl2 & 7] = hx;
        lv[cl2 >> 3][cl2 & 7] = (_Float16)(v - (float)hx);
      }
      if (mat == 0) {
        _Float16* dh = Qh + ((long)b * QPAD + p) * 128 + chanb;
        _Float16* dl = Ql + ((long)b * QPAD + p) * 128 + chanb;
        *(f16x8*)dh = hv[0]; *(f16x8*)(dh + 8) = hv[1];
        *(f16x8*)dl = lv[0]; *(f16x8*)(dl + 8) = lv[1];
      } else {
        _Float16* dk = Kv + ((long)b * NPAD + p) * 128 + chanb;
        *(f16x8*)dk = hv[0]; *(f16x8*)(dk + 8) = hv[1];
      }
    }
  }
}

// ========== flash v4: BM=64, 32 KB LDS (Ps aliases Ks), 3 waves/SIMD ==========
__global__ __launch_bounds__(256, 3) void flash_k(
    const _Float16* __restrict__ Qh, const _Float16* __restrict__ Ql,
    const _Float16* __restrict__ Kv, const _Float16* __restrict__ Vt,
    float* __restrict__ Opart, float* __restrict__ Mp, float* __restrict__ Lp) {
  __shared__ _Float16 Ks[64 * 128];   // 16 KB; after barrier C reused as Ps
  __shared__ _Float16 Vs[128 * 64];   // 16 KB
  int qt = blockIdx.x, split = blockIdx.y, b = blockIdx.z;
  int tid = threadIdx.x, wave = tid >> 6, lane = tid & 63;
  int quad = lane >> 4, l16 = lane & 15;
  const _Float16* Qhb = Qh + (long)b * QPAD * D_;
  const _Float16* Qlb = Ql + (long)b * QPAD * D_;
  const _Float16* Kb  = Kv + (long)b * NPAD * D_;
  const _Float16* Vb  = Vt + (long)b * C2_ * NPAD;

  long qrow = qt * 64 + wave * 16 + l16;
  f16x8 aqh[4], aql[4];
#pragma unroll
  for (int kk = 0; kk < 4; kk++) {
    aqh[kk] = *(const f16x8*)(Qhb + qrow * D_ + kk * 32 + quad * 8);
    aql[kk] = *(const f16x8*)(Qlb + qrow * D_ + kk * 32 + quad * 8);
  }
  f32x4 o_acc[8];
#pragma unroll
  for (int s = 0; s < 8; s++) o_acc[s] = (f32x4){0.f, 0.f, 0.f, 0.f};
  float m_r[4] = {-3e38f, -3e38f, -3e38f, -3e38f};
  float l_r[4] = {0.f, 0.f, 0.f, 0.f};
  const float LOG2E = 1.4426950408889634f;
  int po = wave * 1024;

  int t0 = split * 21, t1 = t0 + 21;
  for (int t = t0; t < t1; t++) {
    __syncthreads();                  // (A) prior PV reads of Ps(=Ks)/Vs done
#pragma unroll
    for (int i = 0; i < 4; i++) {
      int g = tid + i * 256;
      int r = g >> 4, q = g & 15;
      *(f16x8*)&Ks[r * 128 + ((q ^ (r & 15)) << 3)] =
          *(const f16x8*)(Kb + (long)(t * 64 + r) * D_ + q * 8);
      int c = g >> 3, q8 = g & 7;
      *(f16x8*)&Vs[c * 64 + ((q8 ^ (c & 7)) << 3)] =
          *(const f16x8*)(Vb + (long)c * NPAD + t * 64 + q8 * 8);
    }
    __syncthreads();                  // (B) tiles visible

    f32x4 s_acc[4];
#pragma unroll
    for (int s = 0; s < 4; s++) s_acc[s] = (f32x4){0.f, 0.f, 0.f, 0.f};
#pragma unroll
    for (int kk = 0; kk < 4; kk++) {
      f16x8 bh[4];
#pragma unroll
      for (int s = 0; s < 4; s++)
        bh[s] = *(const f16x8*)&Ks[(s * 16 + l16) * 128 + (((kk * 4 + quad) ^ l16) << 3)];
#pragma unroll
      for (int s = 0; s < 4; s++) s_acc[s] = MFMA16(aqh[kk], bh[s], s_acc[s]);
#pragma unroll
      for (int s = 0; s < 4; s++) s_acc[s] = MFMA16(aql[kk], bh[s], s_acc[s]);
    }
    __syncthreads();                  // (C) Ks reads done -> reusable as Ps

#pragma unroll
    for (int s = 0; s < 4; s++) {
      if (t * 64 + s * 16 + l16 >= NSEQ) {
#pragma unroll
        for (int r = 0; r < 4; r++) s_acc[s][r] = -3e38f;
      }
    }
    float mx[4];
#pragma unroll
    for (int r = 0; r < 4; r++) {
      mx[r] = fmaxf(fmaxf(s_acc[0][r], s_acc[1][r]), fmaxf(s_acc[2][r], s_acc[3][r]));
      mx[r] = rmax16(mx[r]);
    }
    float alpha[4];
#pragma unroll
    for (int r = 0; r < 4; r++) {
      float mn = fmaxf(m_r[r], mx[r]);
      alpha[r] = exp2f((m_r[r] - mn) * LOG2E);
      m_r[r] = mn;
    }
    float pvv[4][4], rs[4] = {0.f, 0.f, 0.f, 0.f};
#pragma unroll
    for (int s = 0; s < 4; s++)
#pragma unroll
      for (int r = 0; r < 4; r++) {
        float p = exp2f((s_acc[s][r] - m_r[r]) * LOG2E);
        pvv[s][r] = p;
        rs[r] += p;
      }
#pragma unroll
    for (int r = 0; r < 4; r++) {
      rs[r] = rsum16(rs[r]);
      l_r[r] = l_r[r] * alpha[r] + rs[r];
    }
#pragma unroll
    for (int s8 = 0; s8 < 8; s8++)
#pragma unroll
      for (int r = 0; r < 4; r++) o_acc[s8][r] *= alpha[r];
#pragma unroll
    for (int s = 0; s < 4; s++)
#pragma unroll
      for (int r = 0; r < 4; r++) {
        int m = quad * 4 + r;
        Ks[po + m * 64 + (((s * 2 + (l16 >> 3)) ^ (m & 7)) << 3) + (l16 & 7)] =
            (_Float16)pvv[s][r];
      }
    f16x8 ap[2];
#pragma unroll
    for (int kk2 = 0; kk2 < 2; kk2++)
      ap[kk2] = *(const f16x8*)&Ks[po + l16 * 64 + (((kk2 * 4 + quad) ^ (l16 & 7)) << 3)];
#pragma unroll
    for (int kk2 = 0; kk2 < 2; kk2++)
#pragma unroll
      for (int s8 = 0; s8 < 8; s8++) {
        int c2 = s8 * 16 + l16;
        f16x8 bv = *(const f16x8*)&Vs[c2 * 64 + (((kk2 * 4 + quad) ^ (c2 & 7)) << 3)];
        o_acc[s8] = MFMA16(ap[kk2], bv, o_acc[s8]);
      }
  }
  float* Ob = Opart + (long)(b * SPLITS + split) * NSEQ * D_;
  float* Mb = Mp + (long)(b * SPLITS + split) * NSEQ;
  float* Lb = Lp + (long)(b * SPLITS + split) * NSEQ;
#pragma unroll
  for (int r = 0; r < 4; r++) {
    int n = qt * 64 + wave * 16 + quad * 4 + r;
    if (n < NSEQ) {
#pragma unroll
      for (int s8 = 0; s8 < 8; s8++)
        Ob[(long)n * D_ + s8 * 16 + l16] = o_acc[s8][r];
      if (l16 == 0) { Mb[n] = m_r[r]; Lb[n] = l_r[r]; }
    }
  }
}

// ========== merge split partials ==========
__global__ __launch_bounds__(256) void merge_k(const float* __restrict__ Opart,
                                               const float* __restrict__ Mp,
                                               const float* __restrict__ Lp,
                                               float* __restrict__ Y) {
  int row = blockIdx.x * 4 + (threadIdx.x >> 6);
  int lane = threadIdx.x & 63;
  int b = row / NSEQ, n = row - b * NSEQ;
  const float LOG2E = 1.4426950408889634f;
  float ms[SPLITS], m = -3e38f;
#pragma unroll
  for (int s = 0; s < SPLITS; s++) {
    ms[s] = Mp[(long)(b * SPLITS + s) * NSEQ + n];
    m = fmaxf(m, ms[s]);
  }
  float den = 0.f, a0 = 0.f, a1 = 0.f;
  int d = lane * 2;
#pragma unroll
  for (int s = 0; s < SPLITS; s++) {
    float w = exp2f((ms[s] - m) * LOG2E);
    den += Lp[(long)(b * SPLITS + s) * NSEQ + n] * w;
    const float* O = Opart + ((long)(b * SPLITS + s) * NSEQ + n) * D_ + d;
    a0 += w * O[0];
    a1 += w * O[1];
  }
  float inv = 1.f / den;
  float* Yo = Y + ((long)b * NSEQ + n) * D_ + d;
  Yo[0] = a0 * inv;
  Yo[1] = a1 * inv;
}

// ========== y_w GEMM on raw-viewed y + BN partial stats ==========
__global__ __launch_bounds__(256) void out_k(const float* __restrict__ Y,
                                             const float* __restrict__ yw, float* outp,
                                             float* gsum, float* gsumsq) {
  int b = blockIdx.z, ot = blockIdx.y, pb = blockIdx.x, tid = threadIdx.x;
  __shared__ float Wt[C2_][16];
  __shared__ float red[2][16][4];
#pragma unroll
  for (int i = 0; i < 8; i++) {
    int g = tid + i * 256;
    int r = g >> 7, c = g & 127;
    Wt[c][r] = yw[(ot * 16 + r) * C2_ + c];
  }
  __syncthreads();
  int p0 = pb * 512 + tid;
  const float* Yb = Y + (long)b * NSEQ * D_;
  bool val[2];
#pragma unroll
  for (int j = 0; j < 2; j++) val[j] = (p0 + j * 256) < NSEQ;
  float acc[16][2];
#pragma unroll
  for (int r = 0; r < 16; r++)
#pragma unroll
    for (int j = 0; j < 2; j++) acc[r][j] = 0.f;
  for (int c = 0; c < C2_; c++) {
    float xv[2];
#pragma unroll
    for (int j = 0; j < 2; j++) xv[j] = val[j] ? Yb[(long)c * NSEQ + p0 + j * 256] : 0.f;
#pragma unroll
    for (int r4 = 0; r4 < 4; r4++) {
      f32x4 w4 = *(const f32x4*)&Wt[c][r4 * 4];
#pragma unroll
      for (int rr = 0; rr < 4; rr++)
#pragma unroll
        for (int j = 0; j < 2; j++) acc[r4 * 4 + rr][j] += w4[rr] * xv[j];
    }
  }
  long ob = ((long)b * C_ + ot * 16) * NSEQ;
#pragma unroll
  for (int r = 0; r < 16; r++)
#pragma unroll
    for (int j = 0; j < 2; j++)
      if (val[j]) outp[ob + (long)r * NSEQ + p0 + j * 256] = acc[r][j];
  int wave = tid >> 6, lane = tid & 63;
#pragma unroll
  for (int r = 0; r < 16; r++) {
    float s = 0.f, q = 0.f;
#pragma unroll
    for (int j = 0; j < 2; j++) { s += acc[r][j]; q += acc[r][j] * acc[r][j]; }
#pragma unroll
    for (int off = 1; off < 64; off <<= 1) {
      s += __shfl_xor(s, off, 64);
      q += __shfl_xor(q, off, 64);
    }
    if (lane == 0) { red[0][r][wave] = s; red[1][r][wave] = q; }
  }
  __syncthreads();
  if (tid < 32) {
    int which = tid >> 4, r = tid & 15;
    float v = red[which][r][0] + red[which][r][1] + red[which][r][2] + red[which][r][3];
    atomicAdd((which ? gsumsq : gsum) + ot * 16 + r, v);
  }
}

// ========== BN (training) + residual + relu ==========
__global__ __launch_bounds__(256) void bn_k(const float* __restrict__ outp,
                                            const float* gsum, const float* gsumsq,
                                            const float* __restrict__ bnw,
                                            const float* __restrict__ bnb,
                                            const float* __restrict__ xp, float* out) {
  int idx = blockIdx.x * 256 + threadIdx.x;
  if (idx >= TOT) return;
  int p = idx % NSEQ;
  int bc = idx / NSEQ;
  int c = bc & (C_ - 1);
  const float invn = 1.0f / (float)(B_ * NSEQ);
  float mean = gsum[c] * invn;
  float var = gsumsq[c] * invn - mean * mean;
  var = fmaxf(var, 0.f);
  float is = rsqrtf(var + 1e-5f);
  float v = (outp[idx] - mean) * is * bnw[c] + bnb[c] + xp[(long)bc * NPAD + p];
  out[idx] = fmaxf(v, 0.f);
}

// ========== launcher (6 graph nodes) ==========
extern "C" void kernel_launch(void* const* d_in, const int* in_sizes, int n_in,
                              void* d_out, int out_size, void* d_ws, size_t ws_size,
                              hipStream_t stream) {
  size_t off = 0;
  auto alloc = [&](size_t bytes) -> char* {
    char* p = (char*)d_ws + off;
    off += (bytes + 255) & ~(size_t)255;
    return p;
  };
  float*    xp   = (float*)alloc(sizeof(float) * (size_t)B_ * C_ * NPAD);   // 16.5 MB
  u16*      xpT2 = (u16*)alloc(2 * (size_t)B_ * NPAD * 512);                // 16.5 MB (Mp/Lp later)
  u16*      W2   = (u16*)alloc(2 * (size_t)3 * 128 * 512);                  // 384 KB
  _Float16* Qh   = (_Float16*)alloc(2 * (size_t)B_ * QPAD * D_);            // 4.2 MB (Yb later)
  _Float16* Ql   = (_Float16*)alloc(2 * (size_t)B_ * QPAD * D_);            // 4.2 MB
  _Float16* Kv   = (_Float16*)alloc(2 * (size_t)B_ * NPAD * D_);            // 4.1 MB
  _Float16* Vt   = (_Float16*)alloc(2 * (size_t)B_ * C2_ * NPAD);           // 4.1 MB
  float*    big  = (float*)alloc(sizeof(float) * (size_t)B_ * SPLITS * NSEQ * D_); // 24.4 MB
  float*    gsum = (float*)alloc(1024);
  float*    gsq  = (float*)alloc(1024);

  float* Mp = (float*)xpT2;                 // xpT2 dead after qkv_k
  float* Lp = Mp + (size_t)B_ * SPLITS * NSEQ;
  float* Yb = (float*)Qh;                   // Qh+Ql dead after flash_k (8.4 MB >= 8.1)

  const float* xin = (const float*)d_in[0];
  pool_k<<<dim3(63, 5, B_), 256, 0, stream>>>(xin, xp, xpT2, W2,
                                              (const float*)d_in[1], (const float*)d_in[2],
                                              (const float*)d_in[3], gsum, gsq);
  qkv_k<<<dim3(63, 6, B_), 256, 0, stream>>>(xpT2, W2, Qh, Ql, Kv, Vt);
  flash_k<<<dim3(63, SPLITS, B_), 256, 0, stream>>>(Qh, Ql, Kv, Vt, big, Mp, Lp);
  merge_k<<<3969, 256, 0, stream>>>(big, Mp, Lp, Yb);
  out_k<<<dim3(8, 16, B_), 256, 0, stream>>>(Yb, (const float*)d_in[4], big, gsum, gsq);
  bn_k<<<(TOT + 255) / 256, 256, 0, stream>>>(big, gsum, gsq,
                                              (const float*)d_in[5], (const float*)d_in[6],
                                              xp, (float*)d_out);
}